// Round 13
// baseline (387.196 us; speedup 1.0000x reference)
//
#include <hip/hip_runtime.h>
#include <stdint.h>

#define NM 16
#define HW_P 589824            // 768*768 pixels per mask
#define U8PM 9216              // u64 words per mask
#define C4PM 4608              // uint4 chunks per mask
#define F4PM 147456            // float4s per mask
#define F4PT 2359296           // float4s per tensor
#define PT 512                 // pipeline threads per WG
#define NG 8                   // pipeline WGs (2 columns each)
#define NT 8                   // row tiles (2 rows each)
#define EWG 64                 // election WGs (8*8: pigeonhole winner certain)

typedef unsigned long long u64;
typedef float vf4 __attribute__((ext_vector_type(4)));

// meta words: [0..7] cnt[xcc] | [8] winner | [16..31] flagsA | [32..47] flagsB
// prodflag: u64[7*8] at meta+80: bit63 valid | pca0 0..19 | pca1 20..39 |
//           fa0 bit40 | fa1 bit41
// msg: UNIQUE slot per (boundary g, tile rt): 2 rows = 18432 u64. No reuse ->
// no credits; consumer CU never touched the addresses (write-through stores)
// -> plain coalesced dwordx4 loads are staleness-free (R11-validated).

__device__ __forceinline__ unsigned aload(const unsigned* p) {
    return __hip_atomic_load(p, __ATOMIC_RELAXED, __HIP_MEMORY_SCOPE_AGENT);
}
__device__ __forceinline__ u64 aload64(const u64* p) {
    return __hip_atomic_load(p, __ATOMIC_RELAXED, __HIP_MEMORY_SCOPE_AGENT);
}
__device__ __forceinline__ void astore64(u64* p, u64 v) {
    __hip_atomic_store(p, v, __ATOMIC_RELAXED, __HIP_MEMORY_SCOPE_AGENT);
}
__device__ __forceinline__ unsigned afadd(unsigned* p, unsigned v) {
    return __hip_atomic_fetch_add(p, v, __ATOMIC_RELAXED, __HIP_MEMORY_SCOPE_AGENT);
}

__device__ __forceinline__ uint32_t spread4(uint32_t x) {
    uint32_t t = (x | (x << 12)) & 0x000F000Fu;
    t = (t | (t << 6)) & 0x03030303u;
    t = (t | (t << 3)) & 0x11111111u;
    return t;
}

// ---------------- kernel 1: binarize (coalesced) + meta zero ---------------
__global__ __launch_bounds__(256) void binarize_kernel(
    const float* __restrict__ ma, const float* __restrict__ mb,
    uint32_t* __restrict__ bitsA, uint32_t* __restrict__ bitsB,
    uint4* __restrict__ meta4)
{
    if (blockIdx.x == 0) {          // zero 8 KB of control state (ws is 0xAA,
        uint4 z; z.x = z.y = z.z = z.w = 0u;       // poison has bit63 SET)
        meta4[threadIdx.x] = z;
        meta4[threadIdx.x + 256] = z;
    }
    int g = blockIdx.x * 256 + threadIdx.x;        // float4 index
    int tensor = (g >= F4PT);                      // %64==0: wave-uniform
    int lg = tensor ? (g - F4PT) : g;
    const float* src = tensor ? mb : ma;
    vf4 v = __builtin_nontemporal_load(((const vf4*)src) + lg);
    u64 q0 = __ballot(v.x > 0.0f);
    u64 q1 = __ballot(v.y > 0.0f);
    u64 q2 = __ballot(v.z > 0.0f);
    u64 q3 = __ballot(v.w > 0.0f);
    int lane = threadIdx.x & 63;
    if (lane < 8) {
        uint32_t wd = spread4((uint32_t)(q0 >> (8 * lane)) & 0xFFu)
                    | (spread4((uint32_t)(q1 >> (8 * lane)) & 0xFFu) << 1)
                    | (spread4((uint32_t)(q2 >> (8 * lane)) & 0xFFu) << 2)
                    | (spread4((uint32_t)(q3 >> (8 * lane)) & 0xFFu) << 3);
        uint32_t* bits = tensor ? bitsB : bitsA;
        bits[((lg & ~63) >> 3) + lane] = wd;       // word = 8 float4s
    }
}

// ---------------- kernel 2: same-XCD pipeline, 2-row tiles, 15 hops --------
// 8 groups x 8 two-row tiles -> 15 serial hops (vs 23 with 1-row). Each hop
// resolves a 2x2 pair tile with ONE block reduction via the R12-validated
// 9-term basis-popcount reconstruction (exact inters for every outcome).
__global__ __launch_bounds__(PT, 1) void pipeline_kernel(
    const float* __restrict__ sa, const float* __restrict__ sb,
    uint32_t* bitsA, uint32_t* bitsB, unsigned* meta, u64* msg)
{
    unsigned* cnt    = meta;
    unsigned* winner = meta + 8;
    int* flagsA      = (int*)(meta + 16);
    int* flagsB      = (int*)(meta + 32);
    u64* prodF       = (u64*)(meta + 80);          // [ (g)*8 + rt ]

    const int tid = threadIdx.x;
    const int wave = tid >> 6, lane = tid & 63;

    __shared__ int s_g;
    __shared__ int part[8][12];

    // ---- election (tid0), result broadcast via LDS ----
    if (tid == 0) {
        int xcc;
        asm volatile("s_getreg_b32 %0, hwreg(HW_REG_XCC_ID)" : "=s"(xcc));
        xcc &= 7;
        unsigned slot = afadd(&cnt[xcc], 1u);
        int mine = -1;
        if (slot < NG) {
            if (slot == NG - 1) {
                unsigned exp = 0u;
                __hip_atomic_compare_exchange_strong(
                    winner, &exp, (unsigned)(xcc + 1),
                    __ATOMIC_RELAXED, __ATOMIC_RELAXED, __HIP_MEMORY_SCOPE_AGENT);
            }
            unsigned w;
            while (!(w = aload(winner))) __builtin_amdgcn_s_sleep(1);
            if (w == (unsigned)(xcc + 1)) mine = (int)slot;
        }
        s_g = mine;
    }
    __syncthreads();
    const int g = s_g;
    if (g < 0) return;              // 56 losers exit — zero interference

    const int c0 = 2 * g, c1 = 2 * g + 1;
    uint4* A4 = (uint4*)bitsA;
    uint4* B4 = (uint4*)bitsB;

    u64 b0[18], b1[18];

    auto load18 = [&](const uint4* s4, u64* d) {
#pragma unroll
        for (int w = 0; w < 9; ++w) {
            uint4 q = s4[tid + PT * w];
            d[2 * w]     = ((u64)q.y << 32) | q.x;
            d[2 * w + 1] = ((u64)q.w << 32) | q.z;
        }
    };
    auto store18 = [&](uint4* s4, const u64* d) {
#pragma unroll
        for (int w = 0; w < 9; ++w) {
            uint4 q;
            q.x = (uint32_t)d[2 * w];     q.y = (uint32_t)(d[2 * w] >> 32);
            q.z = (uint32_t)d[2 * w + 1]; q.w = (uint32_t)(d[2 * w + 1] >> 32);
            s4[tid + PT * w] = q;
        }
    };

    // ---- load b columns + popcounts ----
    load18(B4 + (size_t)c0 * C4PM, b0);
    load18(B4 + (size_t)c1 * C4PM, b1);
    int v0 = 0, v1 = 0;
#pragma unroll
    for (int w = 0; w < 18; ++w) { v0 += __popcll(b0[w]); v1 += __popcll(b1[w]); }
#pragma unroll
    for (int off = 32; off >= 1; off >>= 1) {
        v0 += __shfl_xor(v0, off); v1 += __shfl_xor(v1, off);
    }
    if (lane == 0) { part[wave][0] = v0; part[wave][1] = v1; }
    __syncthreads();
    int pcb0 = 0, pcb1 = 0;
#pragma unroll
    for (int w = 0; w < 8; ++w) { pcb0 += part[w][0]; pcb1 += part[w][1]; }
    float sb0 = sb[c0], sb1 = sb[c1];
    int fb0 = 0, fb1 = 0;
    __syncthreads();   // part[] free for stage 0 writes

    for (int rt = 0; rt < NT; ++rt) {
        const int i0 = 2 * rt, i1 = i0 + 1;
        int pca0, pca1, fa0, fa1;
        u64 a0[18], a1[18];

        // ---- obtain rows i0,i1 ----
        if (g == 0) {
            load18(A4 + (size_t)i0 * C4PM, a0);
            load18(A4 + (size_t)i1 * C4PM, a1);
            pca0 = pca1 = 0; fa0 = fa1 = 0;
        } else {
            const u64* fptr = &prodF[(g - 1) * 8 + rt];
            u64 v;
            do { v = aload64(fptr); } while (!(v >> 63));
            asm volatile("" ::: "memory");   // pin data loads below the poll
            pca0 = (int)(v & 0xFFFFF);
            pca1 = (int)((v >> 20) & 0xFFFFF);
            fa0  = (int)((v >> 40) & 1u);
            fa1  = (int)((v >> 41) & 1u);
            const uint4* s4 = (const uint4*)(msg + (size_t)((g - 1) * 8 + rt) * 18432);
            load18(s4, a0);
            load18(s4 + C4PM, a1);
        }

        // ---- 9 basis popcounts (+2 row popcounts for g==0) ----
        int tt[11];
        {
            int s0=0,s1=0,s2=0,s3=0,s4_=0,s5=0,s6=0,s7=0,s8=0,p0=0,p1=0;
#pragma unroll
            for (int w = 0; w < 18; ++w) {
                u64 A0 = a0[w], A1 = a1[w], B0 = b0[w], B1 = b1[w];
                u64 ab  = A0 & B0;
                u64 ab1 = A0 & B1;
                u64 cb  = A1 & B0;
                u64 cb1 = A1 & B1;
                s0 += __popcll(ab);
                s1 += __popcll(ab1);
                s2 += __popcll(ab & B1);
                s3 += __popcll(cb);
                s4_ += __popcll(cb & A0);
                s5 += __popcll(cb1);
                s6 += __popcll(cb1 & A0);
                s7 += __popcll(cb1 & B0);
                s8 += __popcll(cb1 & B0 & A0);
            }
            if (g == 0) {
#pragma unroll
                for (int w = 0; w < 18; ++w) { p0 += __popcll(a0[w]); p1 += __popcll(a1[w]); }
            }
            tt[0]=s0; tt[1]=s1; tt[2]=s2; tt[3]=s3; tt[4]=s4_;
            tt[5]=s5; tt[6]=s6; tt[7]=s7; tt[8]=s8; tt[9]=p0; tt[10]=p1;
        }
#pragma unroll
        for (int off = 32; off >= 1; off >>= 1)
#pragma unroll
            for (int i = 0; i < 11; ++i) tt[i] += __shfl_xor(tt[i], off);
        if (lane == 0) {
#pragma unroll
            for (int i = 0; i < 11; ++i) part[wave][i] = tt[i];
        }
        __syncthreads();   // B2: partials visible, slot loads retired
        int T[9], PC0 = 0, PC1 = 0;
        {
            int acc[11];
#pragma unroll
            for (int i = 0; i < 11; ++i) acc[i] = 0;
#pragma unroll
            for (int w = 0; w < 8; ++w)
#pragma unroll
                for (int i = 0; i < 11; ++i) acc[i] += part[w][i];
#pragma unroll
            for (int i = 0; i < 9; ++i) T[i] = acc[i];
            PC0 = acc[9]; PC1 = acc[10];
        }
        if (g == 0) { pca0 = PC0; pca1 = PC1; }

        float sa0 = sa[i0], sa1 = sa[i1];
        // ---- 4 pairs in reference order; R12-validated basis corrections ---
        bool a0l = false, b0l = false, b1l = false, a1l = false;
        {   // pair (i0, c0)
            int inter = T[0];
            int uni = pca0 + pcb0 - inter;
            float iou = (float)inter / fmaxf((float)uni, 1.0f);
            bool aw = sa0 > sb0;
            if (iou > 0.8f) { if (aw) fb0 = 1; else fa0 = 1; }
            else if (inter > 0) {
                if (aw) { pcb0 -= inter; b0l = true;
#pragma unroll
                          for (int w = 0; w < 18; ++w) b0[w] &= ~a0[w]; }
                else    { pca0 -= inter; a0l = true;
#pragma unroll
                          for (int w = 0; w < 18; ++w) a0[w] &= ~b0[w]; }
            }
        }
        {   // pair (i0, c1)
            int inter = T[1] - (a0l ? T[2] : 0);
            int uni = pca0 + pcb1 - inter;
            float iou = (float)inter / fmaxf((float)uni, 1.0f);
            bool aw = sa0 > sb1;
            if (iou > 0.8f) { if (aw) fb1 = 1; else fa0 = 1; }
            else if (inter > 0) {
                if (aw) { pcb1 -= inter; b1l = true;
#pragma unroll
                          for (int w = 0; w < 18; ++w) b1[w] &= ~a0[w]; }
                else    { pca0 -= inter;
#pragma unroll
                          for (int w = 0; w < 18; ++w) a0[w] &= ~b1[w]; }
            }
        }
        {   // pair (i1, c0)
            int inter = T[3] - (b0l ? T[4] : 0);
            int uni = pca1 + pcb0 - inter;
            float iou = (float)inter / fmaxf((float)uni, 1.0f);
            bool aw = sa1 > sb0;
            if (iou > 0.8f) { if (aw) fb0 = 1; else fa1 = 1; }
            else if (inter > 0) {
                if (aw) { pcb0 -= inter;
#pragma unroll
                          for (int w = 0; w < 18; ++w) b0[w] &= ~a1[w]; }
                else    { pca1 -= inter; a1l = true;
#pragma unroll
                          for (int w = 0; w < 18; ++w) a1[w] &= ~b0[w]; }
            }
        }
        {   // pair (i1, c1)
            int termA = T[5] - (b1l ? (T[6] - (a0l ? T[8] : 0)) : 0);
            int inter = termA;
            if (a1l) {
                int termB = (T[7] - (b0l ? T[8] : 0))
                          - ((b1l && !a0l && !b0l) ? T[8] : 0);
                inter = termA - termB;
            }
            int uni = pca1 + pcb1 - inter;
            float iou = (float)inter / fmaxf((float)uni, 1.0f);
            bool aw = sa1 > sb1;
            if (iou > 0.8f) { if (aw) fb1 = 1; else fa1 = 1; }
            else if (inter > 0) {
                if (aw) { pcb1 -= inter;
#pragma unroll
                          for (int w = 0; w < 18; ++w) b1[w] &= ~a1[w]; }
                else    { pca1 -= inter;
#pragma unroll
                          for (int w = 0; w < 18; ++w) a1[w] &= ~b1[w]; }
            }
        }

        // ---- forward / finalize tile ----
        if (g < NG - 1) {
            uint4* so = (uint4*)(msg + (size_t)(g * 8 + rt) * 18432);
            store18(so, a0);
            store18(so + C4PM, a1);
            __syncthreads();   // B3: every wave's vmcnt(0) -> data visible
            if (tid == 0)      // flag strictly after data
                astore64(&prodF[g * 8 + rt],
                         (1ull << 63) | (u64)(unsigned)pca0
                         | ((u64)(unsigned)pca1 << 20)
                         | ((u64)(unsigned)fa0 << 40) | ((u64)(unsigned)fa1 << 41));
        } else {
            store18(A4 + (size_t)i0 * C4PM, a0);
            store18(A4 + (size_t)i1 * C4PM, a1);
            if (tid == 0) { flagsA[i0] = fa0; flagsA[i1] = fa1; }
            __syncthreads();   // B3: part[] anti-race across stages
        }
    }

    // final b columns + flags; dispatch-end flush publishes to expand
    store18(B4 + (size_t)c0 * C4PM, b0);
    store18(B4 + (size_t)c1 * C4PM, b1);
    if (tid == 0) { flagsB[c0] = fb0; flagsB[c1] = fb1; }
}

// ---------------- kernel 3: expand (coalesced, NT stores) ------------------
__global__ __launch_bounds__(256) void expand_kernel(
    const uint32_t* __restrict__ bitsA, const uint32_t* __restrict__ bitsB,
    const int* __restrict__ meta, float* __restrict__ out)
{
    int g = blockIdx.x * 256 + threadIdx.x;        // float4 index
    int tensor = (g >= F4PT);
    int lg = tensor ? (g - F4PT) : g;
    const uint32_t* bits = tensor ? bitsB : bitsA;
    const int* flags = meta + (tensor ? 32 : 16);
    int m = lg / F4PM;
    bool keep = (flags[m] == 0);
    uint32_t wd = keep ? bits[lg >> 3] : 0u;
    int sh = (lg & 7) * 4;
    vf4 o;
    o.x = ((wd >> (sh + 0)) & 1u) ? 1.0f : 0.0f;
    o.y = ((wd >> (sh + 1)) & 1u) ? 1.0f : 0.0f;
    o.z = ((wd >> (sh + 2)) & 1u) ? 1.0f : 0.0f;
    o.w = ((wd >> (sh + 3)) & 1u) ? 1.0f : 0.0f;
    __builtin_nontemporal_store(o, ((vf4*)out) + g);
    if (g < 2 * NM) {   // keep_a / keep_b tail (flagsA,flagsB contiguous)
        out[(size_t)2 * NM * HW_P + g] = meta[16 + g] ? 0.0f : 1.0f;
    }
}

extern "C" void kernel_launch(void* const* d_in, const int* in_sizes, int n_in,
                              void* d_out, int out_size, void* d_ws, size_t ws_size,
                              hipStream_t stream)
{
    const float* ma = (const float*)d_in[0];
    const float* mb = (const float*)d_in[1];
    const float* sa = (const float*)d_in[2];
    const float* sb = (const float*)d_in[3];
    float* out = (float*)d_out;
    char* ws = (char*)d_ws;

    uint32_t* bitsA = (uint32_t*)(ws);             // 1,179,648 B
    uint32_t* bitsB = (uint32_t*)(ws + 1179648);   // 1,179,648 B
    unsigned* meta  = (unsigned*)(ws + 2359296);   // 8192 B, zeroed by binarize
    u64* msg        = (u64*)(ws + 2367488);        // 56 slots * 147,456 B

    binarize_kernel<<<18432, 256, 0, stream>>>(ma, mb, bitsA, bitsB,
                                               (uint4*)meta);
    pipeline_kernel<<<EWG, PT, 0, stream>>>(sa, sb, bitsA, bitsB, meta, msg);
    expand_kernel<<<18432, 256, 0, stream>>>(bitsA, bitsB, (const int*)meta, out);
}